// Round 17
// baseline (278.954 us; speedup 1.0000x reference)
//
#include <hip/hip_runtime.h>
#include <math.h>

// Problem constants (B=8 batches, N=M=2048 points, D=3)
#define BATCH 8
#define NPTS 2048
#define THREADS 256            // 4 waves: 2 row-groups x 2 col-splits
#define HALF_COLS 1024         // columns staged per LDS stage
#define TILES_H 32             // 32-col MFMA tiles per staged half
#define ROWS_PER_BLOCK 64      // 2 row-groups of 32
#define LOG_M 7.62559580411076 // log(2048)

typedef __attribute__((ext_vector_type(8)))  __bf16 bf16x8;
typedef __attribute__((ext_vector_type(16))) float  f32x16;

union FragU { unsigned short u[8]; uint4 v; };

__device__ __forceinline__ unsigned short f2bf(float f) {
    union { float f; unsigned u; } x; x.f = f;
    unsigned r = x.u + 0x7FFFu + ((x.u >> 16) & 1u);   // RNE
    return (unsigned short)(r >> 16);
}
__device__ __forceinline__ float bf2f(unsigned short b) {
    union { unsigned u; float f; } x; x.u = ((unsigned)b) << 16;
    return x.f;
}

// Single-pass softmin via 32x32x16 MFMA with estimated LSE shift (no max pass).
//   arg_ij = (x'_i . y'_j + pot_j - 0.5|y'_j|^2) * log2(e)/eps  (log2 domain)
// K=16 slots: per dim, (xh,xh,xl,xl)x(yh,yl,yh,yl) = 4 products (12 slots),
// 3-way split of sigma*hhe vs 1.0 (3 slots), slot 15 zero; sigma=log2e/eps.
// Shift m2_hat = (rowconst - old)/k2 enters as the MFMA C operand;
// res = old - k2*log2(s) (rowconst cancels); shift is ~44 log2 units off
// worst-case, inside f32's ~116-unit slack.
// r16 structure (best verified: 261.7 us) + round-17 delta: the inner tile
// loop is explicitly software-pipelined — tile t+1's ds_read+MFMA issue
// BEFORE tile t's acc is consumed by the 16-exp2 burst, hiding the MFMA
// latency (the ~2x stall over the ~10 us/SIMD issue floor). r7's pipeline
// attempt spilled only because launch_bounds(512,4) capped VGPR at 64;
// here LDS (35 KB -> 4 blocks/CU) binds occupancy and the budget is 128.
// Staging uses round-invariant fragments precomputed in round 0 (r16).
// Falsified alternatives kept out: launch_bounds min-arg (r7 spill);
// poly-exp2 (r10); single-kernel fusion (r11/r12); transpose identity
// (r13); 32-row blocks (r15).
// Final round folds the output reduction in via one atomicAdd per block.
// A/B layout: m(n)=lane&31, k=(lane>>5)*8+j.
// C/D layout (verified m74/m101): col=lane&31, row=(reg&3)+8*(reg>>2)+4*(lane>>5).
__global__ __launch_bounds__(THREADS) void softmin_pass(
    const float* __restrict__ x, const float* __restrict__ y,
    const float* __restrict__ potSrc, float* __restrict__ potDst,
    uint4* __restrict__ CF0, uint2* __restrict__ CF1, float* __restrict__ YSQ,
    float sigma, float k2, float inv_k2, float rowc0,
    int avg, int first, int last, float* __restrict__ out)
{
    __shared__ uint4 BF[TILES_H][64];     // 32 KB: B frags (one half), slot=lane
    __shared__ uint4 AF[2][64];           //  2 KB: A frags (2 row-groups)
    __shared__ float NM[ROWS_PER_BLOCK];  // -m2_hat per row
    __shared__ float SRED[2][2][32];      // partial sums [group][colsplit][row]

    const int type  = blockIdx.z;
    const int batch = blockIdx.y;

    const float* rowP;
    const float* colP;
    int hslot, oslot, cs;
    if (type == 0)      { rowP = x; colP = y; hslot = 1; oslot = 0; cs = 1; }  // f_ba
    else if (type == 1) { rowP = y; colP = x; hslot = 0; oslot = 1; cs = 0; }  // g_ab
    else if (type == 2) { rowP = x; colP = x; hslot = 2; oslot = 2; cs = 0; }  // f_aa
    else                { rowP = y; colP = y; hslot = 3; oslot = 3; cs = 1; }  // g_bb

    rowP += batch * NPTS * 3;
    colP += batch * NPTS * 3;
    const float* hP   = potSrc + (hslot * BATCH + batch) * NPTS;
    const float* oldP = potSrc + (oslot * BATCH + batch) * NPTS;
    float*       outP = potDst + (oslot * BATCH + batch) * NPTS;
    const size_t cbase = ((size_t)cs * BATCH + batch) * NPTS;

    // ---- stage A fragments: 2 groups x 64 slots = threads 0..127 ----
    if (threadIdx.x < 128) {
        const int g = threadIdx.x >> 6, idx = threadIdx.x & 63;
        const int row = blockIdx.x * ROWS_PER_BLOCK + g * 32 + (idx & 31);
        float x0 = rowP[3 * row + 0], x1 = rowP[3 * row + 1], x2 = rowP[3 * row + 2];
        float p0 = sigma * (x0 - 0.5f), p1 = sigma * (x1 - 0.5f), p2 = sigma * (x2 - 0.5f);
        unsigned short h0 = f2bf(p0); unsigned short l0 = f2bf(p0 - bf2f(h0));
        unsigned short h1 = f2bf(p1); unsigned short l1 = f2bf(p1 - bf2f(h1));
        unsigned short h2 = f2bf(p2); unsigned short l2 = f2bf(p2 - bf2f(h2));
        FragU f;
        if (idx < 32) {   // k0-7: dim0 (xh,xh,xl,xl), dim1 (xh,xh,xl,xl)
            f.u[0] = h0; f.u[1] = h0; f.u[2] = l0; f.u[3] = l0;
            f.u[4] = h1; f.u[5] = h1; f.u[6] = l1; f.u[7] = l1;
        } else {          // k8-15: dim2 (xh,xh,xl,xl), 1,1,1, 0
            f.u[0] = h2; f.u[1] = h2; f.u[2] = l2; f.u[3] = l2;
            f.u[4] = 0x3F80; f.u[5] = 0x3F80; f.u[6] = 0x3F80; f.u[7] = 0;
        }
        AF[g][idx] = f.v;
    } else if (threadIdx.x < 128 + ROWS_PER_BLOCK) {
        // ---- per-row shift: NM[r] = (old - rowconst)/k2 = -m2_hat ----
        const int r = threadIdx.x - 128;
        const int i = blockIdx.x * ROWS_PER_BLOCK + r;
        float x0 = rowP[3 * i + 0], x1 = rowP[3 * i + 1], x2 = rowP[3 * i + 2];
        float p0 = x0 - 0.5f, p1 = x1 - 0.5f, p2 = x2 - 0.5f;
        float rowconst = 0.5f * (p0 * p0 + p1 * p1 + p2 * p2) + rowc0;
        float oldv = first ? 0.0f : oldP[i];
        NM[r] = (oldv - rowconst) * inv_k2;
    }

    const int lane = threadIdx.x & 63;
    const int wave = threadIdx.x >> 6;
    const int g    = wave >> 1;        // row-group 0..1
    const int c    = wave & 1;         // col-split 0..1
    const int khalf = lane >> 5;

    float s[16];
    #pragma unroll
    for (int r = 0; r < 16; ++r) s[r] = 0.0f;
    bf16x8 af;
    f32x16 nmv;

    // ---- two column halves, BF restaged between them ----
    for (int h = 0; h < 2; ++h) {
        if (h) __syncthreads();   // all waves done reading previous half

        if (first) {
            // slow path: full recompute from coords (pot == 0); the writer
            // block of each (colset,batch) also stores the invariants.
            const int writer = (blockIdx.x == 0) && (type <= 1);
            for (int jj = threadIdx.x; jj < HALF_COLS; jj += THREADS) {
                const int j = h * HALF_COLS + jj;
                float y0 = colP[3 * j + 0], y1 = colP[3 * j + 1], y2 = colP[3 * j + 2];
                float p0 = y0 - 0.5f, p1 = y1 - 0.5f, p2 = y2 - 0.5f;
                unsigned short h0 = f2bf(p0); unsigned short l0 = f2bf(p0 - bf2f(h0));
                unsigned short h1 = f2bf(p1); unsigned short l1 = f2bf(p1 - bf2f(h1));
                unsigned short h2 = f2bf(p2); unsigned short l2 = f2bf(p2 - bf2f(h2));
                float ysq = 0.5f * (p0 * p0 + p1 * p1 + p2 * p2);
                float hhe = -sigma * ysq;                    // pot == 0
                unsigned short hA = f2bf(hhe); float r1 = hhe - bf2f(hA);
                unsigned short hB = f2bf(r1);  float r2 = r1 - bf2f(hB);
                unsigned short hC = f2bf(r2);
                FragU f0, f1;
                // k0-7: dim0 (yh,yl,yh,yl), dim1 (yh,yl,yh,yl)
                f0.u[0] = h0; f0.u[1] = l0; f0.u[2] = h0; f0.u[3] = l0;
                f0.u[4] = h1; f0.u[5] = l1; f0.u[6] = h1; f0.u[7] = l1;
                // k8-15: dim2 (yh,yl,yh,yl), hA,hB,hC, 0
                f1.u[0] = h2; f1.u[1] = l2; f1.u[2] = h2; f1.u[3] = l2;
                f1.u[4] = hA; f1.u[5] = hB; f1.u[6] = hC; f1.u[7] = 0;
                BF[jj >> 5][jj & 31]        = f0.v;   // k0-7  (lanes 0-31)
                BF[jj >> 5][32 + (jj & 31)] = f1.v;   // k8-15 (lanes 32-63)
                if (writer) {
                    CF0[cbase + j] = f0.v;
                    CF1[cbase + j] = make_uint2(f1.v.x, f1.v.y);  // h2,l2,h2,l2
                    YSQ[cbase + j] = ysq;
                }
            }
        } else {
            // fast path: invariants from global (L2-hit), only hhe recomputed
            for (int jj = threadIdx.x; jj < HALF_COLS; jj += THREADS) {
                const int j = h * HALF_COLS + jj;
                uint4 f0  = CF0[cbase + j];
                uint2 f1l = CF1[cbase + j];
                float hhe = sigma * (hP[j] - YSQ[cbase + j]);
                unsigned short hA = f2bf(hhe); float r1 = hhe - bf2f(hA);
                unsigned short hB = f2bf(r1);  float r2 = r1 - bf2f(hB);
                unsigned short hC = f2bf(r2);
                uint4 f1 = make_uint4(f1l.x, f1l.y,
                                      (unsigned)hA | ((unsigned)hB << 16),
                                      (unsigned)hC);
                BF[jj >> 5][jj & 31]        = f0;     // k0-7  (lanes 0-31)
                BF[jj >> 5][32 + (jj & 31)] = f1;     // k8-15 (lanes 32-63)
            }
        }
        __syncthreads();

        if (h == 0) {   // A-frags / NM ready after first barrier
            af = *(const bf16x8*)&AF[g][lane];
            #pragma unroll
            for (int r = 0; r < 16; ++r) {
                const int row = (r & 3) + 8 * (r >> 2) + 4 * khalf;
                nmv[r] = NM[g * 32 + row];
            }
        }

        // this wave's 16 tiles of the staged 32 — software-pipelined:
        // tile t+1's MFMA is in flight while tile t's acc feeds exp2.
        const int tbase = c * (TILES_H / 2);
        {
            f32x16 accp = __builtin_amdgcn_mfma_f32_32x32x16_bf16(
                af, *(const bf16x8*)&BF[tbase][lane], nmv, 0, 0, 0);
            #pragma unroll 3
            for (int t = 1; t < TILES_H / 2; ++t) {
                f32x16 accn = __builtin_amdgcn_mfma_f32_32x32x16_bf16(
                    af, *(const bf16x8*)&BF[tbase + t][lane], nmv, 0, 0, 0);
                #pragma unroll
                for (int r = 0; r < 16; ++r)
                    s[r] += __builtin_amdgcn_exp2f(accp[r]);
                accp = accn;
            }
            #pragma unroll
            for (int r = 0; r < 16; ++r)
                s[r] += __builtin_amdgcn_exp2f(accp[r]);
        }
    }

    // ---- reduce over the 32 cols held across lanes (xor 1..16) ----
    #pragma unroll
    for (int off = 1; off <= 16; off <<= 1)
        #pragma unroll
        for (int r = 0; r < 16; ++r)
            s[r] += __shfl_xor(s[r], off, 64);

    // ---- write col-split partials; merge; epilogue ----
    if ((lane & 31) == 0) {
        #pragma unroll
        for (int r = 0; r < 16; ++r) {
            const int row = (r & 3) + 8 * (r >> 2) + 4 * khalf;
            SRED[g][c][row] = s[r];
        }
    }
    __syncthreads();

    if (threadIdx.x < ROWS_PER_BLOCK) {
        const int p = threadIdx.x >> 5, r = threadIdx.x & 31;
        const int i = blockIdx.x * ROWS_PER_BLOCK + p * 32 + r;
        float sum = SRED[p][0][r] + SRED[p][1][r];
        float oldv = first ? 0.0f : oldP[i];
        float res = oldv - k2 * __log2f(sum);
        outP[i] = avg ? 0.5f * (oldv + res) : res;
        if (last) NM[threadIdx.x] = res;   // stash for the output reduction
    }

    // ---- last round: out[b] += sign * sum(res)/N, one atomic per block ----
    if (last) {
        __syncthreads();
        if (wave == 0) {   // threads 0..63 re-reduce the 64 stashed values
            float v = NM[lane];
            #pragma unroll
            for (int off = 32; off >= 1; off >>= 1)
                v += __shfl_xor(v, off, 64);
            if (lane == 0) {
                float sign = (type >= 2) ? -1.0f : 1.0f;   // f_aa,g_bb subtract
                atomicAdd(out + batch, sign * v * (1.0f / NPTS));
            }
        }
    }
}

extern "C" void kernel_launch(void* const* d_in, const int* in_sizes, int n_in,
                              void* d_out, int out_size, void* d_ws, size_t ws_size,
                              hipStream_t stream)
{
    const float* x = (const float*)d_in[0];
    const float* y = (const float*)d_in[1];
    float* out = (float*)d_out;

    // ws layout: P0, P1 (4 x B x NPTS floats each), then invariant arrays:
    // CF0 (2 x B x NPTS uint4), CF1 (uint2), YSQ (float).
    const size_t potElems = (size_t)4 * BATCH * NPTS;
    const size_t colElems = (size_t)2 * BATCH * NPTS;
    float* P0  = (float*)d_ws;
    float* P1  = P0 + potElems;
    uint4* CF0 = (uint4*)(P1 + potElems);
    uint2* CF1 = (uint2*)(CF0 + colElems);
    float* YSQ = (float*)(CF1 + colElems);
    // No P0 memset: round 0 (first=1) synthesizes zero potentials.

    // Zero the 8 output accumulators (harness poisons d_out each replay).
    hipMemsetAsync(out, 0, BATCH * sizeof(float), stream);

    // Epsilon schedule: [diam^p] + exp(arange(p ln diam, p ln blur, p ln scale)) + [blur^p]
    double epsl[16];
    int ne = 0;
    epsl[ne++] = 4.0;                       // diameter^2
    const double stop = 2.0 * log(0.05);
    const double step = 2.0 * log(0.5);
    for (double e = 2.0 * log(2.0); e > stop; e += step)
        epsl[ne++] = exp(e);                // 4, 1, 0.25, 0.0625, 0.015625, 0.00390625
    epsl[ne++] = 0.05 * 0.05;               // blur^2 = 0.0025

    float* src = P0;
    float* dst = P1;
    dim3 grid(NPTS / ROWS_PER_BLOCK, BATCH, 4);

    auto launch = [&](double eps, int avg, int first, int last) {
        float sigma  = (float)(M_LOG2E / eps);   // K=16, no k-dup
        float k2     = (float)(eps * M_LN2);
        float inv_k2 = (float)(1.0 / (eps * M_LN2));
        float rowc0  = (float)(eps * LOG_M);
        softmin_pass<<<grid, THREADS, 0, stream>>>(
            x, y, src, dst, CF0, CF1, YSQ,
            sigma, k2, inv_k2, rowc0, avg, first, last, out);
        float* t = src; src = dst; dst = t;
    };

    launch(epsl[0], 0, 1, 0);                 // init (writes invariants)
    for (int k = 0; k < ne; ++k)
        launch(epsl[k], 1, 0, 0);             // damped symmetric Sinkhorn
    launch(epsl[ne - 1], 0, 0, 1);            // final extrapolation + output
}

// Round 18
// 260.658 us; speedup vs baseline: 1.0702x; 1.0702x over previous
//
#include <hip/hip_runtime.h>
#include <math.h>

// Problem constants (B=8 batches, N=M=2048 points, D=3)
#define BATCH 8
#define NPTS 2048
#define THREADS 256            // 4 waves: 2 row-groups x 2 col-splits
#define HALF_COLS 1024         // columns staged per LDS stage
#define TILES_H 32             // 32-col MFMA tiles per staged half
#define ROWS_PER_BLOCK 64      // 2 row-groups of 32
#define LOG_M 7.62559580411076 // log(2048)

typedef __attribute__((ext_vector_type(8)))  __bf16 bf16x8;
typedef __attribute__((ext_vector_type(16))) float  f32x16;

union FragU { unsigned short u[8]; uint4 v; };

__device__ __forceinline__ unsigned short f2bf(float f) {
    union { float f; unsigned u; } x; x.f = f;
    unsigned r = x.u + 0x7FFFu + ((x.u >> 16) & 1u);   // RNE
    return (unsigned short)(r >> 16);
}
__device__ __forceinline__ float bf2f(unsigned short b) {
    union { unsigned u; float f; } x; x.u = ((unsigned)b) << 16;
    return x.f;
}

// Single-pass softmin via 32x32x16 MFMA with estimated LSE shift (no max pass).
//   arg_ij = (x'_i . y'_j + pot_j - 0.5|y'_j|^2) * log2(e)/eps  (log2 domain)
// K=16 slots: per dim, (xh,xh,xl,xl)x(yh,yl,yh,yl) = 4 products (12 slots),
// 3-way split of sigma*hhe vs 1.0 (3 slots), slot 15 zero; sigma=log2e/eps.
// Shift m2_hat = (rowconst - old)/k2 enters as the MFMA C operand;
// res = old - k2*log2(s) (rowconst cancels); shift is ~44 log2 units off
// worst-case, inside f32's ~116-unit slack.
// This is the r16 kernel verbatim (best verified: 261.7 us) — the measured
// optimum of this design space. Full falsification record:
//  r7  launch_bounds(512,4) pipeline: 161 MB/dispatch scratch spill
//  r10 hybrid poly-exp2 on VALU: worse (trans shares the wave issue port;
//      v_exp_f32 effectively ~13-16 issue-cyc; poly ~14 cyc/pair no better)
//  r11/r12 single-kernel fusion: grid-barrier + agent fences cost
//      ~28-100 us/round vs ~3 us launch gaps
//  r13 transpose identity (-25% exp2): +32 VGPR colsum state and extra
//      barriers/finalize cost more than the arithmetic saved
//  r15 32-row blocks for 8 waves/SIMD: staging VALU doubles, barriers 4x
//  r17 manual MFMA->exp2 pipeline: +16 VGPR occupancy step + defeats the
//      compiler's own scheduling (261.7 -> 279)
// Kept wins: r14 fold-in of the output reduction (atomicAdd per block);
// r16 round-invariant B-fragment precompute (round 0 stores packed coord
// splits + ysq; rounds 1-9 restage from 28 B L2-resident loads + hhe only).
// A/B layout: m(n)=lane&31, k=(lane>>5)*8+j.
// C/D layout (verified m74/m101): col=lane&31, row=(reg&3)+8*(reg>>2)+4*(lane>>5).
__global__ __launch_bounds__(THREADS) void softmin_pass(
    const float* __restrict__ x, const float* __restrict__ y,
    const float* __restrict__ potSrc, float* __restrict__ potDst,
    uint4* __restrict__ CF0, uint2* __restrict__ CF1, float* __restrict__ YSQ,
    float sigma, float k2, float inv_k2, float rowc0,
    int avg, int first, int last, float* __restrict__ out)
{
    __shared__ uint4 BF[TILES_H][64];     // 32 KB: B frags (one half), slot=lane
    __shared__ uint4 AF[2][64];           //  2 KB: A frags (2 row-groups)
    __shared__ float NM[ROWS_PER_BLOCK];  // -m2_hat per row
    __shared__ float SRED[2][2][32];      // partial sums [group][colsplit][row]

    const int type  = blockIdx.z;
    const int batch = blockIdx.y;

    const float* rowP;
    const float* colP;
    int hslot, oslot, cs;
    if (type == 0)      { rowP = x; colP = y; hslot = 1; oslot = 0; cs = 1; }  // f_ba
    else if (type == 1) { rowP = y; colP = x; hslot = 0; oslot = 1; cs = 0; }  // g_ab
    else if (type == 2) { rowP = x; colP = x; hslot = 2; oslot = 2; cs = 0; }  // f_aa
    else                { rowP = y; colP = y; hslot = 3; oslot = 3; cs = 1; }  // g_bb

    rowP += batch * NPTS * 3;
    colP += batch * NPTS * 3;
    const float* hP   = potSrc + (hslot * BATCH + batch) * NPTS;
    const float* oldP = potSrc + (oslot * BATCH + batch) * NPTS;
    float*       outP = potDst + (oslot * BATCH + batch) * NPTS;
    const size_t cbase = ((size_t)cs * BATCH + batch) * NPTS;

    // ---- stage A fragments: 2 groups x 64 slots = threads 0..127 ----
    if (threadIdx.x < 128) {
        const int g = threadIdx.x >> 6, idx = threadIdx.x & 63;
        const int row = blockIdx.x * ROWS_PER_BLOCK + g * 32 + (idx & 31);
        float x0 = rowP[3 * row + 0], x1 = rowP[3 * row + 1], x2 = rowP[3 * row + 2];
        float p0 = sigma * (x0 - 0.5f), p1 = sigma * (x1 - 0.5f), p2 = sigma * (x2 - 0.5f);
        unsigned short h0 = f2bf(p0); unsigned short l0 = f2bf(p0 - bf2f(h0));
        unsigned short h1 = f2bf(p1); unsigned short l1 = f2bf(p1 - bf2f(h1));
        unsigned short h2 = f2bf(p2); unsigned short l2 = f2bf(p2 - bf2f(h2));
        FragU f;
        if (idx < 32) {   // k0-7: dim0 (xh,xh,xl,xl), dim1 (xh,xh,xl,xl)
            f.u[0] = h0; f.u[1] = h0; f.u[2] = l0; f.u[3] = l0;
            f.u[4] = h1; f.u[5] = h1; f.u[6] = l1; f.u[7] = l1;
        } else {          // k8-15: dim2 (xh,xh,xl,xl), 1,1,1, 0
            f.u[0] = h2; f.u[1] = h2; f.u[2] = l2; f.u[3] = l2;
            f.u[4] = 0x3F80; f.u[5] = 0x3F80; f.u[6] = 0x3F80; f.u[7] = 0;
        }
        AF[g][idx] = f.v;
    } else if (threadIdx.x < 128 + ROWS_PER_BLOCK) {
        // ---- per-row shift: NM[r] = (old - rowconst)/k2 = -m2_hat ----
        const int r = threadIdx.x - 128;
        const int i = blockIdx.x * ROWS_PER_BLOCK + r;
        float x0 = rowP[3 * i + 0], x1 = rowP[3 * i + 1], x2 = rowP[3 * i + 2];
        float p0 = x0 - 0.5f, p1 = x1 - 0.5f, p2 = x2 - 0.5f;
        float rowconst = 0.5f * (p0 * p0 + p1 * p1 + p2 * p2) + rowc0;
        float oldv = first ? 0.0f : oldP[i];
        NM[r] = (oldv - rowconst) * inv_k2;
    }

    const int lane = threadIdx.x & 63;
    const int wave = threadIdx.x >> 6;
    const int g    = wave >> 1;        // row-group 0..1
    const int c    = wave & 1;         // col-split 0..1
    const int khalf = lane >> 5;

    float s[16];
    #pragma unroll
    for (int r = 0; r < 16; ++r) s[r] = 0.0f;
    bf16x8 af;
    f32x16 nmv;

    // ---- two column halves, BF restaged between them ----
    for (int h = 0; h < 2; ++h) {
        if (h) __syncthreads();   // all waves done reading previous half

        if (first) {
            // slow path: full recompute from coords (pot == 0); the writer
            // block of each (colset,batch) also stores the invariants.
            const int writer = (blockIdx.x == 0) && (type <= 1);
            for (int jj = threadIdx.x; jj < HALF_COLS; jj += THREADS) {
                const int j = h * HALF_COLS + jj;
                float y0 = colP[3 * j + 0], y1 = colP[3 * j + 1], y2 = colP[3 * j + 2];
                float p0 = y0 - 0.5f, p1 = y1 - 0.5f, p2 = y2 - 0.5f;
                unsigned short h0 = f2bf(p0); unsigned short l0 = f2bf(p0 - bf2f(h0));
                unsigned short h1 = f2bf(p1); unsigned short l1 = f2bf(p1 - bf2f(h1));
                unsigned short h2 = f2bf(p2); unsigned short l2 = f2bf(p2 - bf2f(h2));
                float ysq = 0.5f * (p0 * p0 + p1 * p1 + p2 * p2);
                float hhe = -sigma * ysq;                    // pot == 0
                unsigned short hA = f2bf(hhe); float r1 = hhe - bf2f(hA);
                unsigned short hB = f2bf(r1);  float r2 = r1 - bf2f(hB);
                unsigned short hC = f2bf(r2);
                FragU f0, f1;
                // k0-7: dim0 (yh,yl,yh,yl), dim1 (yh,yl,yh,yl)
                f0.u[0] = h0; f0.u[1] = l0; f0.u[2] = h0; f0.u[3] = l0;
                f0.u[4] = h1; f0.u[5] = l1; f0.u[6] = h1; f0.u[7] = l1;
                // k8-15: dim2 (yh,yl,yh,yl), hA,hB,hC, 0
                f1.u[0] = h2; f1.u[1] = l2; f1.u[2] = h2; f1.u[3] = l2;
                f1.u[4] = hA; f1.u[5] = hB; f1.u[6] = hC; f1.u[7] = 0;
                BF[jj >> 5][jj & 31]        = f0.v;   // k0-7  (lanes 0-31)
                BF[jj >> 5][32 + (jj & 31)] = f1.v;   // k8-15 (lanes 32-63)
                if (writer) {
                    CF0[cbase + j] = f0.v;
                    CF1[cbase + j] = make_uint2(f1.v.x, f1.v.y);  // h2,l2,h2,l2
                    YSQ[cbase + j] = ysq;
                }
            }
        } else {
            // fast path: invariants from global (L2-hit), only hhe recomputed
            for (int jj = threadIdx.x; jj < HALF_COLS; jj += THREADS) {
                const int j = h * HALF_COLS + jj;
                uint4 f0  = CF0[cbase + j];
                uint2 f1l = CF1[cbase + j];
                float hhe = sigma * (hP[j] - YSQ[cbase + j]);
                unsigned short hA = f2bf(hhe); float r1 = hhe - bf2f(hA);
                unsigned short hB = f2bf(r1);  float r2 = r1 - bf2f(hB);
                unsigned short hC = f2bf(r2);
                uint4 f1 = make_uint4(f1l.x, f1l.y,
                                      (unsigned)hA | ((unsigned)hB << 16),
                                      (unsigned)hC);
                BF[jj >> 5][jj & 31]        = f0;     // k0-7  (lanes 0-31)
                BF[jj >> 5][32 + (jj & 31)] = f1;     // k8-15 (lanes 32-63)
            }
        }
        __syncthreads();

        if (h == 0) {   // A-frags / NM ready after first barrier
            af = *(const bf16x8*)&AF[g][lane];
            #pragma unroll
            for (int r = 0; r < 16; ++r) {
                const int row = (r & 3) + 8 * (r >> 2) + 4 * khalf;
                nmv[r] = NM[g * 32 + row];
            }
        }

        // this wave's 16 tiles of the staged 32
        const int tbase = c * (TILES_H / 2);
        #pragma unroll 2
        for (int t = 0; t < TILES_H / 2; ++t) {
            bf16x8 bf = *(const bf16x8*)&BF[tbase + t][lane];
            f32x16 acc = __builtin_amdgcn_mfma_f32_32x32x16_bf16(af, bf, nmv, 0, 0, 0);
            #pragma unroll
            for (int r = 0; r < 16; ++r)
                s[r] += __builtin_amdgcn_exp2f(acc[r]);
        }
    }

    // ---- reduce over the 32 cols held across lanes (xor 1..16) ----
    #pragma unroll
    for (int off = 1; off <= 16; off <<= 1)
        #pragma unroll
        for (int r = 0; r < 16; ++r)
            s[r] += __shfl_xor(s[r], off, 64);

    // ---- write col-split partials; merge; epilogue ----
    if ((lane & 31) == 0) {
        #pragma unroll
        for (int r = 0; r < 16; ++r) {
            const int row = (r & 3) + 8 * (r >> 2) + 4 * khalf;
            SRED[g][c][row] = s[r];
        }
    }
    __syncthreads();

    if (threadIdx.x < ROWS_PER_BLOCK) {
        const int p = threadIdx.x >> 5, r = threadIdx.x & 31;
        const int i = blockIdx.x * ROWS_PER_BLOCK + p * 32 + r;
        float sum = SRED[p][0][r] + SRED[p][1][r];
        float oldv = first ? 0.0f : oldP[i];
        float res = oldv - k2 * __log2f(sum);
        outP[i] = avg ? 0.5f * (oldv + res) : res;
        if (last) NM[threadIdx.x] = res;   // stash for the output reduction
    }

    // ---- last round: out[b] += sign * sum(res)/N, one atomic per block ----
    if (last) {
        __syncthreads();
        if (wave == 0) {   // threads 0..63 re-reduce the 64 stashed values
            float v = NM[lane];
            #pragma unroll
            for (int off = 32; off >= 1; off >>= 1)
                v += __shfl_xor(v, off, 64);
            if (lane == 0) {
                float sign = (type >= 2) ? -1.0f : 1.0f;   // f_aa,g_bb subtract
                atomicAdd(out + batch, sign * v * (1.0f / NPTS));
            }
        }
    }
}

extern "C" void kernel_launch(void* const* d_in, const int* in_sizes, int n_in,
                              void* d_out, int out_size, void* d_ws, size_t ws_size,
                              hipStream_t stream)
{
    const float* x = (const float*)d_in[0];
    const float* y = (const float*)d_in[1];
    float* out = (float*)d_out;

    // ws layout: P0, P1 (4 x B x NPTS floats each), then invariant arrays:
    // CF0 (2 x B x NPTS uint4), CF1 (uint2), YSQ (float).
    const size_t potElems = (size_t)4 * BATCH * NPTS;
    const size_t colElems = (size_t)2 * BATCH * NPTS;
    float* P0  = (float*)d_ws;
    float* P1  = P0 + potElems;
    uint4* CF0 = (uint4*)(P1 + potElems);
    uint2* CF1 = (uint2*)(CF0 + colElems);
    float* YSQ = (float*)(CF1 + colElems);
    // No P0 memset: round 0 (first=1) synthesizes zero potentials.

    // Zero the 8 output accumulators (harness poisons d_out each replay).
    hipMemsetAsync(out, 0, BATCH * sizeof(float), stream);

    // Epsilon schedule: [diam^p] + exp(arange(p ln diam, p ln blur, p ln scale)) + [blur^p]
    double epsl[16];
    int ne = 0;
    epsl[ne++] = 4.0;                       // diameter^2
    const double stop = 2.0 * log(0.05);
    const double step = 2.0 * log(0.5);
    for (double e = 2.0 * log(2.0); e > stop; e += step)
        epsl[ne++] = exp(e);                // 4, 1, 0.25, 0.0625, 0.015625, 0.00390625
    epsl[ne++] = 0.05 * 0.05;               // blur^2 = 0.0025

    float* src = P0;
    float* dst = P1;
    dim3 grid(NPTS / ROWS_PER_BLOCK, BATCH, 4);

    auto launch = [&](double eps, int avg, int first, int last) {
        float sigma  = (float)(M_LOG2E / eps);   // K=16, no k-dup
        float k2     = (float)(eps * M_LN2);
        float inv_k2 = (float)(1.0 / (eps * M_LN2));
        float rowc0  = (float)(eps * LOG_M);
        softmin_pass<<<grid, THREADS, 0, stream>>>(
            x, y, src, dst, CF0, CF1, YSQ,
            sigma, k2, inv_k2, rowc0, avg, first, last, out);
        float* t = src; src = dst; dst = t;
    };

    launch(epsl[0], 0, 1, 0);                 // init (writes invariants)
    for (int k = 0; k < ne; ++k)
        launch(epsl[k], 1, 0, 0);             // damped symmetric Sinkhorn
    launch(epsl[ne - 1], 0, 0, 1);            // final extrapolation + output
}